// Round 6
// baseline (289.124 us; speedup 1.0000x reference)
//
#include <hip/hip_runtime.h>
#include <math.h>

#define NF 16
#define VOCAB 100000
#define S1 28      // conv1 plane stride, dwords per pair-row
#define PB 868     // plane B base (dwords) = 31*S1
#define S2 20      // conv2 plane stride, dwords per row
#define PLW 1736   // total plane LDS dwords (conv2 plane aliases onto it)
#define REDS 1700  // cross-wave reduction slots (dead zone during epilogue)

typedef _Float16 h2 __attribute__((ext_vector_type(2)));

#if __has_builtin(__builtin_amdgcn_fdot2)
#define FDOT2(a, b, c) __builtin_amdgcn_fdot2((a), (b), (c), false)
#else
#define FDOT2(a, b, c) ((float)(a)[0] * (float)(b)[0] + ((float)(a)[1] * (float)(b)[1] + (c)))
#endif

__device__ __forceinline__ float tanhf_fast(float x) {
    float e = __expf(2.f * x);
    return 1.f - 2.f * __builtin_amdgcn_rcpf(e + 1.f);
}

__device__ __forceinline__ h2 u2h(unsigned int u) {
    union { unsigned int u; h2 h; } c; c.u = u; return c.h;
}

// Per-output-channel packed fp16-pair filter tables in ws:
// F1: ws[o*128 + j*8 + kw]       = {f1[2j][kw][o], f1[2j+1][kw][o]}     j<16, kw<7
// F2: ws[256 + o*256 + kh*8 + kw] = {f2[kh][kw][0][o], f2[kh][kw][1][o]} kh<32, kw<5
__global__ void pack_filters(const float* __restrict__ f1,
                             const float* __restrict__ f2,
                             unsigned int* __restrict__ ws) {
    int t = threadIdx.x;
    if (t < 224) {
        int o = t / 112, r = t % 112, j = r / 7, kw = r % 7;
        h2 h;
        h[0] = (_Float16)f1[((2 * j) * 7 + kw) * 2 + o];
        h[1] = (_Float16)f1[((2 * j + 1) * 7 + kw) * 2 + o];
        union { h2 h; unsigned int u; } c; c.h = h;
        ws[o * 128 + j * 8 + kw] = c.u;
    }
    for (int n = t; n < 320; n += 256) {
        int o = n / 160, r = n % 160, kh = r / 5, kw = r % 5;
        h2 h;
        h[0] = (_Float16)f2[(kh * 5 + kw) * 4 + o];
        h[1] = (_Float16)f2[(kh * 5 + kw) * 4 + 2 + o];
        union { h2 h; unsigned int u; } c; c.h = h;
        ws[256 + o * 256 + kh * 8 + kw] = c.u;
    }
}

__global__ __launch_bounds__(128, 8) void ccpm_fwd(
    const int* __restrict__ idx,
    const float* __restrict__ w0,
    const float* __restrict__ b0,
    const float* __restrict__ w1,
    const float* __restrict__ b1,
    const unsigned int* __restrict__ FP,
    float* __restrict__ out)
{
    const int b = blockIdx.x;
    const int t = threadIdx.x;

    __shared__ __align__(16) unsigned int lds[PLW];   // 6944 B

    const float4 z4 = make_float4(0.f, 0.f, 0.f, 0.f);

    // ---- phase 0: zero both conv1 planes ----
    #pragma unroll
    for (int i = 0; i < 4; ++i) {
        int n = i * 128 + t;
        if (n < PLW / 4) ((float4*)lds)[n] = z4;
    }
    __syncthreads();

    // ---- phase 1: embedding gather + bias + tanh -> both row-interleaved planes ----
    {
        int f  = t >> 3;            // 0..15
        int e0 = (t & 7) * 4;       // 0,4,...,28
        int row = idx[b * NF + f];
        float4 v = *(const float4*)(w0 + ((size_t)f * VOCAB + row) * 32 + e0);
        float4 u = *(const float4*)(b0 + f * 32 + e0);
        float g[4] = {v.x + u.x, v.y + u.y, v.z + u.z, v.w + u.w};
        _Float16* H = (_Float16*)lds;
        const int C = f + 3;
        #pragma unroll
        for (int i = 0; i < 4; ++i) {
            int R = e0 + i + 15;                      // padded row, 15..46
            _Float16 hv = (_Float16)tanhf_fast(g[i]);
            H[((R >> 1) * S1 + C) * 2 + (R & 1)] = hv;      // plane A (rows 2pr,2pr+1)
            int prB = (R & 1) ? (R >> 1) : (R >> 1) - 1;    // plane B (rows 2pr+1,2pr+2)
            H[(PB + prB * S1 + C) * 2 + ((R & 1) ^ 1)] = hv;
        }
    }
    __syncthreads();

    const int h    = t & 31;        // output row e
    const int half = (t >> 5) & 1;  // w-half
    const int o    = t >> 6;        // output channel == wave id (uniform per wave)

    // ---- phase 2: conv1 (32x7 SAME), kh-paired dot2, one channel per wave ----
    float a[8];
    {
        #pragma unroll
        for (int w = 0; w < 8; ++w) a[w] = 0.f;
        const unsigned int* plane = lds + ((h & 1) ? PB : 0);
        const int pr0 = h >> 1;
        const int cb  = half * 8;
        const unsigned int* ft = FP + o * 128;        // wave-uniform -> s_load
        #pragma unroll 2
        for (int j = 0; j < 16; ++j) {                // kh pair (2j, 2j+1)
            const unsigned int* rb = plane + (pr0 + j) * S1 + cb;
            uint4 q0 = ((const uint4*)rb)[0];
            uint4 q1 = ((const uint4*)rb)[1];
            uint4 q2 = ((const uint4*)rb)[2];
            uint2 q3 = *(const uint2*)(rb + 12);
            unsigned int win[14] = {q0.x,q0.y,q0.z,q0.w, q1.x,q1.y,q1.z,q1.w,
                                    q2.x,q2.y,q2.z,q2.w, q3.x,q3.y};
            #pragma unroll
            for (int kw = 0; kw < 7; ++kw) {
                h2 fp = u2h(ft[j * 8 + kw]);
                #pragma unroll
                for (int w = 0; w < 8; ++w)
                    a[w] = FDOT2(u2h(win[w + kw]), fp, a[w]);
            }
        }
    }

    // pool1 value assembly (wave-local shfl, no barrier)
    float v16[16];
    {
        #pragma unroll
        for (int i = 0; i < 8; ++i) {
            float recv = __shfl_xor(a[i], 32, 64);
            v16[half ? 8 + i : i]  = a[i];
            v16[half ? i : 8 + i]  = recv;
        }
    }
    __syncthreads();            // all conv1 plane reads complete

    // ---- phase 3: zero conv2 plane region (63 rows x S2 dwords = 315 float4) ----
    #pragma unroll
    for (int i = 0; i < 3; ++i) {
        int n = i * 128 + t;
        if (n < 315) ((float4*)lds)[n] = z4;
    }
    __syncthreads();

    // ---- phase 4: pool1 top-8 of 16 -> conv2 plane (i-channels packed per dword) ----
    {
        int r16[16];
        #pragma unroll
        for (int i = 0; i < 16; ++i) r16[i] = 0;
        #pragma unroll
        for (int i = 0; i < 16; ++i)
            #pragma unroll
            for (int j = i + 1; j < 16; ++j) {
                bool ge = v16[i] >= v16[j];           // tie -> earlier index wins
                r16[j] += ge ? 1 : 0;
                r16[i] += ge ? 0 : 1;
            }
        if (half == 0) {
            _Float16* H = (_Float16*)lds;
            #pragma unroll
            for (int i = 0; i < 16; ++i)
                if (r16[i] < 8)
                    H[((h + 15) * S2 + (r16[i] + 2)) * 2 + o] = (_Float16)v16[i];
        }
    }
    __syncthreads();

    // ---- phase 5: conv2 (32x5x2 SAME), i-paired dot2, one channel per wave ----
    float c[4];
    {
        #pragma unroll
        for (int w = 0; w < 4; ++w) c[w] = 0.f;
        const int cb2 = half * 4;
        const unsigned int* ft2 = FP + 256 + o * 256; // wave-uniform -> s_load
        #pragma unroll 2
        for (int kh = 0; kh < 32; ++kh) {
            const unsigned int* rb = lds + (h + kh) * S2 + cb2;
            uint4 qa = ((const uint4*)rb)[0];
            uint4 qb = ((const uint4*)rb)[1];
            unsigned int q[8] = {qa.x,qa.y,qa.z,qa.w, qb.x,qb.y,qb.z,qb.w};
            #pragma unroll
            for (int kw = 0; kw < 5; ++kw) {
                h2 fp = u2h(ft2[kh * 8 + kw]);
                #pragma unroll
                for (int w = 0; w < 4; ++w)
                    c[w] = FDOT2(u2h(q[w + kw]), fp, c[w]);
            }
        }
    }

    // ---- phase 6: pool2 top-3 of 8 + tanh + dot(w1) + cross-wave reduce + sigmoid ----
    {
        float v8[8];
        #pragma unroll
        for (int i = 0; i < 4; ++i) {
            float recv = __shfl_xor(c[i], 32, 64);
            v8[half ? 4 + i : i] = c[i];
            v8[half ? i : 4 + i] = recv;
        }
        int r8[8];
        #pragma unroll
        for (int i = 0; i < 8; ++i) r8[i] = 0;
        #pragma unroll
        for (int i = 0; i < 8; ++i)
            #pragma unroll
            for (int j = i + 1; j < 8; ++j) {
                bool ge = v8[i] >= v8[j];
                r8[j] += ge ? 1 : 0;
                r8[i] += ge ? 0 : 1;
            }
        float t0 = 0.f, t1 = 0.f, t2 = 0.f;
        #pragma unroll
        for (int i = 0; i < 8; ++i) {
            t0 = (r8[i] == 0) ? v8[i] : t0;
            t1 = (r8[i] == 1) ? v8[i] : t1;
            t2 = (r8[i] == 2) ? v8[i] : t2;
        }
        float s = tanhf_fast(t0) * w1[h * 6 + o]
                + tanhf_fast(t1) * w1[h * 6 + 2 + o]
                + tanhf_fast(t2) * w1[h * 6 + 4 + o];
        s = half ? 0.f : s;                  // each (h,o) contributes once
        #pragma unroll
        for (int off = 32; off; off >>= 1) s += __shfl_xor(s, off, 64);
        if ((t & 63) == 0) ((float*)lds)[REDS + o] = s;
    }
    __syncthreads();
    if (t == 0) {
        float logit = ((float*)lds)[REDS] + ((float*)lds)[REDS + 1] + b1[0];
        out[b] = __builtin_amdgcn_rcpf(1.f + __expf(-logit));
    }
}

extern "C" void kernel_launch(void* const* d_in, const int* in_sizes, int n_in,
                              void* d_out, int out_size, void* d_ws, size_t ws_size,
                              hipStream_t stream) {
    const int*   idx = (const int*)d_in[0];
    const float* w0  = (const float*)d_in[1];
    const float* b0  = (const float*)d_in[2];
    const float* f1  = (const float*)d_in[3];
    const float* f2  = (const float*)d_in[4];
    const float* w1  = (const float*)d_in[5];
    const float* b1  = (const float*)d_in[6];
    float* out = (float*)d_out;
    unsigned int* ws = (unsigned int*)d_ws;

    pack_filters<<<1, 256, 0, stream>>>(f1, f2, ws);
    ccpm_fwd<<<out_size, 128, 0, stream>>>(idx, w0, b0, w1, b1, ws, out);
}